// Round 1
// baseline (102.323 us; speedup 1.0000x reference)
//
#include <hip/hip_runtime.h>
#include <math.h>

#define BS 16
#define NGT 64
#define NA 8400
#define NCLS 80
#define TOPK 9
#define NCAND 27

__device__ __forceinline__ float pair_iou(float gx1, float gy1, float gx2, float gy2,
                                          float ax1, float ay1, float ax2, float ay2) {
    // _pairwise_iou semantics: unclamped areas, union = max(a1+a2-ov, 1e-6)
    float ltx = fmaxf(gx1, ax1), lty = fmaxf(gy1, ay1);
    float rbx = fminf(gx2, ax2), rby = fminf(gy2, ay2);
    float w = fmaxf(rbx - ltx, 0.0f), h = fmaxf(rby - lty, 0.0f);
    float ov = w * h;
    float a1 = (gx2 - gx1) * (gy2 - gy1);
    float a2 = (ax2 - ax1) * (ay2 - ay1);
    float uni = fmaxf(a1 + a2 - ov, 1e-6f);
    return ov / uni;
}

// K1: one block per (b,g). Compute distances in LDS, exact per-level top-9
// (iterative argmin, first-index tie-break == lax.top_k), mean+std(ddof=1)
// threshold over the 27 candidate IoUs, write sparse mask_pos.
__global__ __launch_bounds__(256) void k1_candidates(
        const float* __restrict__ anc, const float* __restrict__ gtb,
        const float* __restrict__ mgt, unsigned char* __restrict__ mask_pos) {
    const int blk = blockIdx.x;           // b*NGT + g
    const int tid = threadIdx.x;

    __shared__ float sdist[NA];
    __shared__ float rval[256];
    __shared__ int   ridx[256];
    __shared__ int   cand[NCAND];
    __shared__ float sov[NCAND];
    __shared__ float sthr;

    const float gx1 = gtb[blk * 4 + 0], gy1 = gtb[blk * 4 + 1];
    const float gx2 = gtb[blk * 4 + 2], gy2 = gtb[blk * 4 + 3];
    const float gcx = (gx1 + gx2) * 0.5f, gcy = (gy1 + gy2) * 0.5f;

    unsigned char* mrow = mask_pos + (size_t)blk * NA;
    for (int a = tid; a < NA; a += 256) {
        float ax1 = anc[a * 4 + 0], ay1 = anc[a * 4 + 1];
        float ax2 = anc[a * 4 + 2], ay2 = anc[a * 4 + 3];
        float acx = (ax1 + ax2) * 0.5f, acy = (ay1 + ay2) * 0.5f;
        float dx = gcx - acx, dy = gcy - acy;
        sdist[a] = sqrtf(dx * dx + dy * dy);
        mrow[a] = 0;
    }
    __syncthreads();

    if (!(mgt[blk] > 0.0f)) return;   // invalid gt: row stays zero (uniform exit)

    const int starts[4] = {0, 6400, 8000, 8400};
    int cn = 0;
    for (int lev = 0; lev < 3; ++lev) {
        const int s = starts[lev], e = starts[lev + 1];
        for (int it = 0; it < TOPK; ++it) {
            float bv = 3.4e38f; int bi = 0x7fffffff;
            for (int a = s + tid; a < e; a += 256) {
                float v = sdist[a];
                if (v < bv) { bv = v; bi = a; }   // ascending a => first-index on tie
            }
            rval[tid] = bv; ridx[tid] = bi;
            __syncthreads();
            for (int off = 128; off > 0; off >>= 1) {
                if (tid < off) {
                    float v2 = rval[tid + off]; int i2 = ridx[tid + off];
                    if (v2 < rval[tid] || (v2 == rval[tid] && i2 < ridx[tid])) {
                        rval[tid] = v2; ridx[tid] = i2;
                    }
                }
                __syncthreads();
            }
            if (tid == 0) { cand[cn] = ridx[0]; sdist[ridx[0]] = 3.4e38f; }
            __syncthreads();
            ++cn;
        }
    }

    // candidate IoUs (recomputed on the fly; overlaps tensor never materialized)
    if (tid < NCAND) {
        int a = cand[tid];
        sov[tid] = pair_iou(gx1, gy1, gx2, gy2,
                            anc[a * 4 + 0], anc[a * 4 + 1], anc[a * 4 + 2], anc[a * 4 + 3]);
    }
    __syncthreads();
    if (tid == 0) {
        float sum = 0.0f;
        for (int j = 0; j < NCAND; ++j) sum += sov[j];
        float mean = sum / (float)NCAND;
        float vs = 0.0f;
        for (int j = 0; j < NCAND; ++j) { float d = sov[j] - mean; vs += d * d; }
        sthr = mean + sqrtf(vs / (float)(NCAND - 1));   // ddof=1
    }
    __syncthreads();
    if (tid < NCAND) {
        int a = cand[tid];
        float ax1 = anc[a * 4 + 0], ay1 = anc[a * 4 + 1];
        float ax2 = anc[a * 4 + 2], ay2 = anc[a * 4 + 3];
        float acx = (ax1 + ax2) * 0.5f, acy = (ay1 + ay2) * 0.5f;
        float mn = fminf(fminf(acx - gx1, acy - gy1), fminf(gx2 - acx, gy2 - acy));
        if (sov[tid] > sthr && mn > 1e-9f) mrow[a] = 1;   // strict >, EPS=1e-9
    }
}

// K2: one thread per (b,a). Resolve multi-assignment (argmax over recomputed
// pairwise IoUs, first-max), gather label/bbox, compute _batch_iou vs pd box.
__global__ __launch_bounds__(256) void k2_assign(
        const float* __restrict__ anc, const int* __restrict__ glab,
        const float* __restrict__ gtb, const float* __restrict__ pdb,
        const unsigned char* __restrict__ mask_pos,
        float* __restrict__ out, int* __restrict__ wlab, float* __restrict__ wval) {
    const int idx = blockIdx.x * 256 + threadIdx.x;
    if (idx >= BS * NA) return;
    const int b = idx / NA, a = idx - b * NA;

    const unsigned char* mp = mask_pos + (size_t)b * NGT * NA + a;
    int fg = 0, tgi = -1;
    for (int g = 0; g < NGT; ++g) {
        if (mp[(size_t)g * NA]) { if (tgi < 0) tgi = g; ++fg; }
    }
    if (fg > 1) {   // mask_multi -> is_max over ALL gts (incl. invalid), first-max
        float ax1 = anc[a * 4 + 0], ay1 = anc[a * 4 + 1];
        float ax2 = anc[a * 4 + 2], ay2 = anc[a * 4 + 3];
        float best = -1.0f; int gi = 0;
        for (int g = 0; g < NGT; ++g) {
            const float* gp = gtb + (b * NGT + g) * 4;
            float v = pair_iou(gp[0], gp[1], gp[2], gp[3], ax1, ay1, ax2, ay2);
            if (v > best) { best = v; gi = g; }
        }
        tgi = gi;
    }
    const bool pos = fg > 0;
    if (!pos) tgi = 0;   // argmax of all-zero row = 0; bbox still gathered

    const int lbl = pos ? glab[b * NGT + tgi] : NCLS;
    const float* gp = gtb + (b * NGT + tgi) * 4;

    float sval = 0.0f;
    if (pos) {
        // _batch_iou semantics: clamped areas, union = a1+a2-ov+1e-9 (no max)
        const float* pp = pdb + (size_t)(b * NA + a) * 4;
        float ltx = fmaxf(gp[0], pp[0]), lty = fmaxf(gp[1], pp[1]);
        float rbx = fminf(gp[2], pp[2]), rby = fminf(gp[3], pp[3]);
        float ov = fmaxf(rbx - ltx, 0.0f) * fmaxf(rby - lty, 0.0f);
        float a1 = fmaxf(gp[2] - gp[0], 0.0f) * fmaxf(gp[3] - gp[1], 0.0f);
        float a2 = fmaxf(pp[2] - pp[0], 0.0f) * fmaxf(pp[3] - pp[1], 0.0f);
        sval = ov / (a1 + a2 - ov + 1e-9f);
    }

    out[idx] = (float)lbl;                                  // target_labels
    float* ob = out + (size_t)BS * NA + (size_t)idx * 4;    // target_bboxes
    ob[0] = gp[0]; ob[1] = gp[1]; ob[2] = gp[2]; ob[3] = gp[3];
    out[(size_t)BS * NA * 85 + idx] = pos ? 1.0f : 0.0f;    // fg_mask (after scores)
    wlab[idx] = lbl;
    wval[idx] = sval;
}

// K3: streaming one-hot * max-iou scatter into the 16x8400x80 score block.
__global__ __launch_bounds__(256) void k3_scores(
        const int* __restrict__ wlab, const float* __restrict__ wval,
        float* __restrict__ oscore) {
    const int i = blockIdx.x * 256 + threadIdx.x;
    if (i >= BS * NA * NCLS) return;
    const int ba = i / NCLS;
    const int c = i - ba * NCLS;
    oscore[i] = (c == wlab[ba]) ? wval[ba] : 0.0f;
}

extern "C" void kernel_launch(void* const* d_in, const int* in_sizes, int n_in,
                              void* d_out, int out_size, void* d_ws, size_t ws_size,
                              hipStream_t stream) {
    const float* anc  = (const float*)d_in[0];
    const int*   glab = (const int*)d_in[1];
    const float* gtb  = (const float*)d_in[2];
    const float* mgt  = (const float*)d_in[3];
    const float* pdb  = (const float*)d_in[4];
    float* out = (float*)d_out;

    // ws layout: mask_pos (16*64*8400 u8) | wlab (134400 i32) | wval (134400 f32)
    unsigned char* mask_pos = (unsigned char*)d_ws;
    char* p = (char*)d_ws + (size_t)BS * NGT * NA;
    int*   wlab = (int*)p;
    float* wval = (float*)(p + (size_t)BS * NA * 4);

    k1_candidates<<<BS * NGT, 256, 0, stream>>>(anc, gtb, mgt, mask_pos);
    k2_assign<<<(BS * NA + 255) / 256, 256, 0, stream>>>(anc, glab, gtb, pdb, mask_pos,
                                                         out, wlab, wval);
    k3_scores<<<(BS * NA * NCLS + 255) / 256, 256, 0, stream>>>(
        wlab, wval, out + (size_t)BS * NA * 5);
}